// Round 5
// baseline (124.027 us; speedup 1.0000x reference)
//
#include <hip/hip_runtime.h>

// Problem: B=2, S=2048, E=1024, H=16, D=64. ALL FP32 (in and out).
// Reference einsum 'bhqk,bvhd->bqhd' sums k and v SEPARATELY:
//   out[b,q,h,d] = (sum_k softmax) * (sum_s v[b,s,h,d]) = sum_s v[b,s,h,d]
// => out_row[b,:] = colsum(values[b]) @ Wv^T + S*bv, broadcast over all q.
// Q/K path mathematically dead (softmax rows sum to 1).
//
// R4 passed (absmax 0.25, dur 121 us). Top-5 dispatches were harness poison
// fills (41 us each) — our kernels are small. This round: 5 dispatches -> 3.
// K1 partial colsums (no atomics/memset), K2 reduce+matvec fused, K3 bcast.

#define BB 2
#define SS 2048
#define EE 1024

constexpr int NCH = 128;       // partial chunks per batch
constexpr int CH  = SS / NCH;  // 16 rows per chunk

// ---------------- K1: partial[b,c,e] = sum_{s in chunk c} values[b,s,e] ---
__global__ void colsum_partial_kernel(const float* __restrict__ values,
                                      float* __restrict__ partial) {
    const int tid = threadIdx.x;          // 256 threads, 4 e's each
    const int b   = blockIdx.x & 1;
    const int c   = blockIdx.x >> 1;      // [0, NCH)
    const int e0  = tid * 4;
    const float* p =
        values + (size_t)b * SS * EE + (size_t)c * CH * EE + e0;
    float4 a = {0.f, 0.f, 0.f, 0.f};
    #pragma unroll
    for (int s = 0; s < CH; ++s) {
        float4 u = *reinterpret_cast<const float4*>(p + (size_t)s * EE);
        a.x += u.x; a.y += u.y; a.z += u.z; a.w += u.w;
    }
    *reinterpret_cast<float4*>(partial + ((size_t)(b * NCH + c)) * EE + e0) = a;
}

// ---------------- K2: reduce partials -> x (LDS), then out_row = x@Wv^T ---
// Grid: 32 blocks = b(2) x 16 j-groups of 64 j each; 256 threads (4 waves).
__global__ void reduce_matvec_kernel(const float* __restrict__ Wv,
                                     const float* __restrict__ bv,
                                     const float* __restrict__ partial,
                                     float* __restrict__ out_row) {
    __shared__ float sm[EE];
    const int tid = threadIdx.x;
    const int b   = blockIdx.x >> 4;      // 0..1
    const int jg  = blockIdx.x & 15;      // 0..15 -> j0 = jg*64
    // Phase A: x[e] = sum_c partial[b,c,e]
    {
        const int e0 = tid * 4;
        const float* p = partial + (size_t)b * NCH * EE + e0;
        float4 a = {0.f, 0.f, 0.f, 0.f};
        #pragma unroll 8
        for (int c = 0; c < NCH; ++c) {
            float4 u = *reinterpret_cast<const float4*>(p + (size_t)c * EE);
            a.x += u.x; a.y += u.y; a.z += u.z; a.w += u.w;
        }
        *reinterpret_cast<float4*>(sm + e0) = a;
    }
    __syncthreads();
    // Phase B: 4 waves x 16 j's each; y_j = sum_e x_e * Wv[j,e] + S*bv[j]
    const int wave = tid >> 6;
    const int lane = tid & 63;
    #pragma unroll
    for (int jj = 0; jj < 16; ++jj) {
        const int j = jg * 64 + wave * 16 + jj;
        const float* w = Wv + (size_t)j * EE;
        float acc = 0.f;
        #pragma unroll
        for (int i = 0; i < EE / 256; ++i) {   // 4 iters, float4 per lane
            int e = i * 256 + lane * 4;
            float4 wv = *reinterpret_cast<const float4*>(w + e);
            float4 xv = *reinterpret_cast<const float4*>(sm + e);
            acc += wv.x * xv.x + wv.y * xv.y + wv.z * xv.z + wv.w * xv.w;
        }
        #pragma unroll
        for (int off = 32; off; off >>= 1) acc += __shfl_down(acc, off, 64);
        if (lane == 0)
            out_row[b * EE + j] = acc + (float)SS * bv[j];
    }
}

// ---------------- K3: broadcast out_row across all q, fp32 stores ---------
__global__ void bcast_kernel(const float* __restrict__ out_row,
                             float* __restrict__ out) {
    const size_t idx = (size_t)blockIdx.x * blockDim.x + threadIdx.x;
    const size_t pos = idx * 4;              // 4 floats (16 B) per thread
    const int e = (int)(pos & (EE - 1));
    const int b = (int)(pos / ((size_t)SS * EE));
    const float4 v = *reinterpret_cast<const float4*>(out_row + b * EE + e);
    *reinterpret_cast<float4*>(out + pos) = v;
}

extern "C" void kernel_launch(void* const* d_in, const int* in_sizes, int n_in,
                              void* d_out, int out_size, void* d_ws, size_t ws_size,
                              hipStream_t stream) {
    // setup_inputs order: values, keys, queries, Wv, bv, Wk, bk, Wq, bq
    const float* values = (const float*)d_in[0];
    const float* Wv     = (const float*)d_in[3];
    const float* bv     = (const float*)d_in[4];
    float* out = (float*)d_out;

    float* partial = (float*)d_ws;                    // BB*NCH*EE floats (1 MB)
    float* out_row = partial + (size_t)BB * NCH * EE; // BB*EE floats

    colsum_partial_kernel<<<BB * NCH, 256, 0, stream>>>(values, partial);

    reduce_matvec_kernel<<<32, 256, 0, stream>>>(Wv, bv, partial, out_row);

    const size_t total = (size_t)BB * SS * EE;        // 4,194,304 floats
    bcast_kernel<<<(unsigned int)(total / 4 / 256), 256, 0, stream>>>(
        out_row, out);
}